// Round 9
// baseline (53.910 us; speedup 1.0000x reference)
//
#include <hip/hip_runtime.h>
#include <hip/hip_bf16.h>

#define NB 16
#define NT 128
#define NR 8192
#define NC 91
#define IOU_TH 0.7f

#define PROPS_PER_BLK 32                      // 2 interleaved 16-proposal tiles
#define GRID_MAIN (NB * NR / PROPS_PER_BLK)   // 4096 blocks
#define BLK_PER_B (GRID_MAIN / NB)            // 256

__device__ __forceinline__ float fastdiv(float a, float b) {
    return a * __builtin_amdgcn_rcpf(b);      // 1-ulp fast divide
}
__device__ __forceinline__ float smooth_l1(float x) {
    float ax = fabsf(x);
    return ax < 1.0f ? 0.5f * x * x : ax - 0.5f;
}

// IoU of proposal box pr vs lane's 8 register-resident targets; returns packed
// (iou_bits&~0x7F) | (127-t)  -> u32 max == (max iou, first-occurrence argmax).
__device__ __forceinline__ unsigned int iou_phase(const float4 (&tb)[8], int l,
                                                  const float4 pr) {
    const float a0 = pr.x, a1 = pr.y, a2 = pr.z, a3 = pr.w;
    const float area_a = (a2 - a0) * (a3 - a1);
    unsigned int bu = 0u;
    #pragma unroll
    for (int j = 0; j < 8; ++j) {
        const float itp = fmaxf(a0, tb[j].x);
        const float il  = fmaxf(a1, tb[j].y);
        const float ib  = fminf(a2, tb[j].z);
        const float ir  = fminf(a3, tb[j].w);
        const float inter  = fmaxf(ib - itp, 0.f) * fmaxf(ir - il, 0.f);
        const float area_b = (tb[j].z - tb[j].x) * (tb[j].w - tb[j].y);
        const float iou = fastdiv(inter, (area_a + area_b) - inter);
        const unsigned int u = (__float_as_uint(iou) & 0xFFFFFF80u)
                             | (127u - (unsigned int)(l + 16 * j));
        bu = max(bu, u);
    }
    return bu;
}

// exp-sum + packed (logit,c) max over the lane's 6 classes (unconditional).
__device__ __forceinline__ void ce_phase(const float (&v)[6], int l,
                                         float& s, unsigned int& cb) {
    s = 0.f; cb = 0u;
    #pragma unroll
    for (int j = 0; j < 6; ++j) {
        const int c = l + 16 * j;
        const bool valid = (c < NC);
        s += valid ? __expf(v[j]) : 0.f;
        unsigned int sb = __float_as_uint(v[j]);
        sb = (sb & 0x80000000u) ? ~sb : (sb | 0x80000000u);   // monotone order map
        const unsigned int cu = (sb & 0xFFFFFF80u) | (127u - (unsigned int)c);
        cb = valid ? max(cb, cu) : cb;
    }
}

// Two proposals per 16-lane group, processed as independent ILP chains:
// CE is computed unconditionally (85%+ positives) so it never waits on the
// IoU reduce; all 6 shuffle-reduce chains run interleaved in one 4-step loop.
__global__ __launch_bounds__(256) void frcnn_main(
    const float* __restrict__ nms_reg,
    const float* __restrict__ rcnn_reg,
    const float* __restrict__ rcnn_cls,
    const float* __restrict__ bboxes,
    const int* __restrict__ classes,
    const int* __restrict__ reduction,
    float4* __restrict__ part)
{
    __shared__ float4 sbox[NT];
    __shared__ int    scls[NT];
    __shared__ float4 sred[4];

    const int b   = blockIdx.x >> 8;              // 256 blocks per batch
    const int blk = blockIdx.x & (BLK_PER_B - 1);
    const int grp = threadIdx.x >> 4;             // 0..15
    const int l   = threadIdx.x & 15;

    if (threadIdx.x < NT) {
        sbox[threadIdx.x] = ((const float4*)bboxes)[b * NT + threadIdx.x];
        scls[threadIdx.x] = classes[b * NT + threadIdx.x];
    }
    __syncthreads();

    // lane l's 8 target boxes (t = l+16j) in registers
    float4 tb[8];
    #pragma unroll
    for (int j = 0; j < 8; ++j) tb[j] = sbox[l + 16 * j];

    const int rv = *reduction;
    float redv;
    if (rv >= 1 && rv <= 65536) redv = (float)rv; // int scalar (expected 16)
    else redv = __int_as_float(rv);               // defensive: f32-encoded
    const float rredv = __builtin_amdgcn_rcpf(redv);

    const size_t pA = (size_t)b * NR + blk * PROPS_PER_BLK + grp;
    const size_t pB = pA + 16;

    // ---- all loads up front (independent of everything) ----
    const float4 prA = ((const float4*)nms_reg)[pA];
    const float4 prB = ((const float4*)nms_reg)[pB];
    const float4 rrA = ((const float4*)rcnn_reg)[pA];
    const float4 rrB = ((const float4*)rcnn_reg)[pB];
    const float* rowA = rcnn_cls + pA * NC;
    const float* rowB = rcnn_cls + pB * NC;
    float vA[6], vB[6];
    #pragma unroll
    for (int j = 0; j < 6; ++j) {
        const int c  = l + 16 * j;
        const int cc = (c < NC) ? c : (NC - 1);
        vA[j] = rowA[cc];                          // coalesced 64B segments
        vB[j] = rowB[cc];
    }

    // ---- two independent IoU chains + two independent CE chains ----
    unsigned int buA = iou_phase(tb, l, prA);
    unsigned int buB = iou_phase(tb, l, prB);
    float sA, sB; unsigned int cbA, cbB;
    ce_phase(vA, l, sA, cbA);
    ce_phase(vB, l, sB, cbB);

    // ---- 6 reduce chains interleaved (pipelined shfl latency) ----
    #pragma unroll
    for (int mk = 8; mk; mk >>= 1) {
        buA = max(buA, __shfl_xor(buA, mk, 16));
        buB = max(buB, __shfl_xor(buB, mk, 16));
        sA += __shfl_xor(sA, mk, 16);
        sB += __shfl_xor(sB, mk, 16);
        cbA = max(cbA, __shfl_xor(cbA, mk, 16));
        cbB = max(cbB, __shfl_xor(cbB, mk, 16));
    }

    float cnt = 0.f, nll = 0.f, reg = 0.f, corr = 0.f;

    auto join = [&](unsigned int bu, float s, unsigned int cb,
                    const float (&v)[6], const float4 rr) {
        const float best = __uint_as_float(bu & 0xFFFFFF80u);
        if (best > IOU_TH) {                       // group-uniform
            const int bidx = 127 - (int)(bu & 127u);
            const int cls  = scls[bidx];
            const int am   = 127 - (int)(cb & 127u);

            const int jj = cls >> 4;               // row[cls] from registers
            float val = v[0];
            val = (jj == 1) ? v[1] : val;
            val = (jj == 2) ? v[2] : val;
            val = (jj == 3) ? v[3] : val;
            val = (jj == 4) ? v[4] : val;
            val = (jj == 5) ? v[5] : val;
            const float lc = __shfl(val, cls & 15, 16);

            if (l == 0) {
                cnt  += 1.f;
                nll  += __logf(s) - lc;
                corr += (am == cls) ? 1.f : 0.f;

                const float4 bb = sbox[bidx];
                const float rd0 = rintf(bb.x * rredv) * redv;
                const float rd1 = rintf(bb.y * rredv) * redv;
                const float rd2 = rintf(bb.z * rredv) * redv;
                const float rd3 = rintf(bb.w * rredv) * redv;
                float hgt = rd2 - rd0; if (hgt == 0.f) hgt = 1.f;
                float wid = rd3 - rd1; if (wid == 0.f) wid = 1.f;
                const float rh = __builtin_amdgcn_rcpf(hgt);
                const float rw = __builtin_amdgcn_rcpf(wid);

                reg += smooth_l1(rr.x - (bb.x - rd0) * rh)
                     + smooth_l1(rr.y - (bb.y - rd1) * rw)
                     + smooth_l1(rr.z - (bb.z - rd2) * rh)
                     + smooth_l1(rr.w - (bb.w - rd3) * rw);
            }
        }
    };
    join(buA, sA, cbA, vA, rrA);
    join(buB, sB, cbB, vB, rrB);

    // ---- block reduction: values live only on lanes {0,16,32,48} ----
    cnt  += __shfl_down(cnt,  32); nll  += __shfl_down(nll,  32);
    reg  += __shfl_down(reg,  32); corr += __shfl_down(corr, 32);
    cnt  += __shfl_down(cnt,  16); nll  += __shfl_down(nll,  16);
    reg  += __shfl_down(reg,  16); corr += __shfl_down(corr, 16);

    const int lane = threadIdx.x & 63;
    const int w    = threadIdx.x >> 6;
    if (lane == 0) sred[w] = make_float4(cnt, nll, reg, corr);
    __syncthreads();
    if (threadIdx.x == 0) {
        float4 t = make_float4(0.f, 0.f, 0.f, 0.f);
        #pragma unroll
        for (int i = 0; i < 4; ++i) {
            t.x += sred[i].x; t.y += sred[i].y; t.z += sred[i].z; t.w += sred[i].w;
        }
        part[blockIdx.x] = t;
    }
}

// Single-block tree reduce of the 4096 float4 partials + finalize.
__global__ __launch_bounds__(1024) void frcnn_reduce(
    const float4* __restrict__ part, float* __restrict__ out)
{
    __shared__ float4 sw[16];
    float4 s = make_float4(0.f, 0.f, 0.f, 0.f);
    for (int i = threadIdx.x; i < GRID_MAIN; i += 1024) {
        const float4 p = part[i];
        s.x += p.x; s.y += p.y; s.z += p.z; s.w += p.w;
    }
    #pragma unroll
    for (int off = 32; off > 0; off >>= 1) {
        s.x += __shfl_down(s.x, off);
        s.y += __shfl_down(s.y, off);
        s.z += __shfl_down(s.z, off);
        s.w += __shfl_down(s.w, off);
    }
    const int lane = threadIdx.x & 63;
    const int w    = threadIdx.x >> 6;
    if (lane == 0) sw[w] = s;
    __syncthreads();
    if (threadIdx.x == 0) {
        float4 t = make_float4(0.f, 0.f, 0.f, 0.f);
        #pragma unroll
        for (int i = 0; i < 16; ++i) {
            t.x += sw[i].x; t.y += sw[i].y; t.z += sw[i].z; t.w += sw[i].w;
        }
        const float pos   = (t.x > 0.f) ? 1.f : 0.f;
        const float denom = fmaxf(t.x, 1.f);
        out[0] = t.y / denom * pos;   // cls_loss
        out[1] = t.z / denom * pos;   // reg_loss
        out[2] = t.w / denom * pos;   // accuracy
    }
}

extern "C" void kernel_launch(void* const* d_in, const int* in_sizes, int n_in,
                              void* d_out, int out_size, void* d_ws, size_t ws_size,
                              hipStream_t stream) {
    // setup_inputs order: nms_reg, nms_cls(unused), rcnn_reg, rcnn_cls, bboxes, classes, reduction
    const float* nms_reg  = (const float*)d_in[0];
    const float* rcnn_reg = (const float*)d_in[2];
    const float* rcnn_cls = (const float*)d_in[3];
    const float* bboxes   = (const float*)d_in[4];
    const int*   classes  = (const int*)d_in[5];
    const int*   red      = (const int*)d_in[6];

    float4* part = (float4*)d_ws;   // 4096 * 16 B = 64 KiB, fully rewritten each launch

    frcnn_main<<<GRID_MAIN, 256, 0, stream>>>(nms_reg, rcnn_reg, rcnn_cls, bboxes,
                                              classes, red, part);
    frcnn_reduce<<<1, 1024, 0, stream>>>(part, (float*)d_out);
}

// Round 10
// 28.093 us; speedup vs baseline: 1.9190x; 1.9190x over previous
//
#include <hip/hip_runtime.h>
#include <hip/hip_bf16.h>

#define NB 16
#define NT 128
#define NR 8192
#define NC 91
#define IOU_TH 0.7f

#define PROPS_PER_BLK 32                      // 2 proposals per 16-lane group
#define GRID_MAIN (NB * NR / PROPS_PER_BLK)   // 4096 blocks
#define BLK_PER_B (GRID_MAIN / NB)            // 256

__device__ __forceinline__ float fastdiv(float a, float b) {
    return a * __builtin_amdgcn_rcpf(b);      // 1-ulp fast divide
}
__device__ __forceinline__ float smooth_l1(float x) {
    float ax = fabsf(x);
    return ax < 1.0f ? 0.5f * x * x : ax - 0.5f;
}
__device__ __forceinline__ unsigned int mono(float x) {   // order-preserving f32->u32
    const unsigned int sb = __float_as_uint(x);
    return (sb & 0x80000000u) ? ~sb : (sb | 0x80000000u);
}

// CE accumulate for one scalar logit (packed argmax: low 7 bits = 127-c)
#define CE_ACC(vv, c, s, cb)                                                    \
    {                                                                           \
        s += __expf(vv);                                                        \
        cb = max(cb, (mono(vv) & 0xFFFFFF80u) | (127u - (unsigned int)(c)));    \
    }

// Post-reduce join for one proposal (pure textual inline -> no address-taking)
#define JOIN(bu, s, cb, v0, v1, v2, v3, v4, v5, rr)                             \
    {                                                                           \
        const float best = __uint_as_float((bu) & 0xFFFFFF80u);                 \
        if (best > IOU_TH) {                                                    \
            const int bidx = 127 - (int)((bu) & 127u);                          \
            const int cls  = scls[bidx];                                        \
            const int am   = 127 - (int)((cb) & 127u);                          \
            const int jj   = cls >> 4;                                          \
            float val = v0;                                                     \
            val = (jj == 1) ? v1 : val;                                         \
            val = (jj == 2) ? v2 : val;                                         \
            val = (jj == 3) ? v3 : val;                                         \
            val = (jj == 4) ? v4 : val;                                         \
            val = (jj == 5) ? v5 : val;                                         \
            const float lc = __shfl(val, cls & 15, 16);                         \
            if (l == 0) {                                                       \
                cnt  += 1.f;                                                    \
                nll  += __logf(s) - lc;                                         \
                corr += (am == cls) ? 1.f : 0.f;                                \
                const float4 bb = sbox[bidx];                                   \
                const float rd0 = rintf(bb.x * rredv) * redv;                   \
                const float rd1 = rintf(bb.y * rredv) * redv;                   \
                const float rd2 = rintf(bb.z * rredv) * redv;                   \
                const float rd3 = rintf(bb.w * rredv) * redv;                   \
                float hgt = rd2 - rd0; if (hgt == 0.f) hgt = 1.f;               \
                float wid = rd3 - rd1; if (wid == 0.f) wid = 1.f;               \
                const float rh = __builtin_amdgcn_rcpf(hgt);                    \
                const float rw = __builtin_amdgcn_rcpf(wid);                    \
                reg += smooth_l1((rr).x - (bb.x - rd0) * rh)                    \
                     + smooth_l1((rr).y - (bb.y - rd1) * rw)                    \
                     + smooth_l1((rr).z - (bb.z - rd2) * rh)                    \
                     + smooth_l1((rr).w - (bb.w - rd3) * rw);                   \
            }                                                                   \
        }                                                                       \
    }

// Two proposals per 16-lane group; CE computed unconditionally (~86% positives)
// so it's independent of the IoU reduce; 6 shuffle-reduce chains interleaved.
// ALL per-thread data in named scalars / unrolled reg arrays (LDS must be 3072,
// not 15360 -- round 9's array-by-reference spilled logits to LDS scratch).
__global__ __launch_bounds__(256) void frcnn_main(
    const float* __restrict__ nms_reg,
    const float* __restrict__ rcnn_reg,
    const float* __restrict__ rcnn_cls,
    const float* __restrict__ bboxes,
    const int* __restrict__ classes,
    const int* __restrict__ reduction,
    float4* __restrict__ part)
{
    __shared__ float4 sbox[NT];
    __shared__ int    scls[NT];
    __shared__ float4 sred[4];

    const int b   = blockIdx.x >> 8;              // 256 blocks per batch
    const int blk = blockIdx.x & (BLK_PER_B - 1);
    const int grp = threadIdx.x >> 4;             // 0..15
    const int l   = threadIdx.x & 15;

    if (threadIdx.x < NT) {
        sbox[threadIdx.x] = ((const float4*)bboxes)[b * NT + threadIdx.x];
        scls[threadIdx.x] = classes[b * NT + threadIdx.x];
    }
    __syncthreads();

    // lane l's 8 target boxes (t = l+16j), plain unrolled register array
    float4 tb[8];
    #pragma unroll
    for (int j = 0; j < 8; ++j) tb[j] = sbox[l + 16 * j];

    const int rv = *reduction;
    float redv;
    if (rv >= 1 && rv <= 65536) redv = (float)rv; // int scalar (expected 16)
    else redv = __int_as_float(rv);               // defensive: f32-encoded
    const float rredv = __builtin_amdgcn_rcpf(redv);

    const size_t pA = (size_t)b * NR + blk * PROPS_PER_BLK + grp;
    const size_t pB = pA + 16;

    // ---- all global loads up front ----
    const float4 prA = ((const float4*)nms_reg)[pA];
    const float4 prB = ((const float4*)nms_reg)[pB];
    const float4 rrA = ((const float4*)rcnn_reg)[pA];
    const float4 rrB = ((const float4*)rcnn_reg)[pB];
    const float* rowA = rcnn_cls + pA * NC;
    const float* rowB = rcnn_cls + pB * NC;
    const int  c5     = l + 80;
    const bool v5ok   = (c5 < NC);                // l < 11
    const int  c5c    = v5ok ? c5 : (NC - 1);
    const float vA0 = rowA[l],      vB0 = rowB[l];
    const float vA1 = rowA[l + 16], vB1 = rowB[l + 16];
    const float vA2 = rowA[l + 32], vB2 = rowB[l + 32];
    const float vA3 = rowA[l + 48], vB3 = rowB[l + 48];
    const float vA4 = rowA[l + 64], vB4 = rowB[l + 64];
    const float vA5 = rowA[c5c],    vB5 = rowB[c5c];

    // ---- IoU chains for A and B, interleaved (independent ILP) ----
    const float areaA = (prA.z - prA.x) * (prA.w - prA.y);
    const float areaB = (prB.z - prB.x) * (prB.w - prB.y);
    unsigned int buA = 0u, buB = 0u;
    #pragma unroll
    for (int j = 0; j < 8; ++j) {
        const float4 t = tb[j];
        const float ab = (t.z - t.x) * (t.w - t.y);
        const unsigned int tag = 127u - (unsigned int)(l + 16 * j);
        {
            const float itp = fmaxf(prA.x, t.x), il = fmaxf(prA.y, t.y);
            const float ib  = fminf(prA.z, t.z), ir = fminf(prA.w, t.w);
            const float inter = fmaxf(ib - itp, 0.f) * fmaxf(ir - il, 0.f);
            const float iou = fastdiv(inter, (areaA + ab) - inter);
            buA = max(buA, (__float_as_uint(iou) & 0xFFFFFF80u) | tag);
        }
        {
            const float itp = fmaxf(prB.x, t.x), il = fmaxf(prB.y, t.y);
            const float ib  = fminf(prB.z, t.z), ir = fminf(prB.w, t.w);
            const float inter = fmaxf(ib - itp, 0.f) * fmaxf(ir - il, 0.f);
            const float iou = fastdiv(inter, (areaB + ab) - inter);
            buB = max(buB, (__float_as_uint(iou) & 0xFFFFFF80u) | tag);
        }
    }

    // ---- CE chains (unconditional; independent of IoU result) ----
    float sA = 0.f, sB = 0.f;
    unsigned int cbA = 0u, cbB = 0u;
    CE_ACC(vA0, l,      sA, cbA);  CE_ACC(vB0, l,      sB, cbB);
    CE_ACC(vA1, l + 16, sA, cbA);  CE_ACC(vB1, l + 16, sB, cbB);
    CE_ACC(vA2, l + 32, sA, cbA);  CE_ACC(vB2, l + 32, sB, cbB);
    CE_ACC(vA3, l + 48, sA, cbA);  CE_ACC(vB3, l + 48, sB, cbB);
    CE_ACC(vA4, l + 64, sA, cbA);  CE_ACC(vB4, l + 64, sB, cbB);
    if (v5ok) {
        CE_ACC(vA5, c5, sA, cbA);
        CE_ACC(vB5, c5, sB, cbB);
    }

    // ---- 6 reduce chains interleaved (pipelined shfl latency) ----
    #pragma unroll
    for (int mk = 8; mk; mk >>= 1) {
        buA = max(buA, __shfl_xor(buA, mk, 16));
        buB = max(buB, __shfl_xor(buB, mk, 16));
        sA += __shfl_xor(sA, mk, 16);
        sB += __shfl_xor(sB, mk, 16);
        cbA = max(cbA, __shfl_xor(cbA, mk, 16));
        cbB = max(cbB, __shfl_xor(cbB, mk, 16));
    }

    float cnt = 0.f, nll = 0.f, reg = 0.f, corr = 0.f;
    JOIN(buA, sA, cbA, vA0, vA1, vA2, vA3, vA4, vA5, rrA);
    JOIN(buB, sB, cbB, vB0, vB1, vB2, vB3, vB4, vB5, rrB);

    // ---- block reduction: values live only on lanes {0,16,32,48} ----
    cnt  += __shfl_down(cnt,  32); nll  += __shfl_down(nll,  32);
    reg  += __shfl_down(reg,  32); corr += __shfl_down(corr, 32);
    cnt  += __shfl_down(cnt,  16); nll  += __shfl_down(nll,  16);
    reg  += __shfl_down(reg,  16); corr += __shfl_down(corr, 16);

    const int lane = threadIdx.x & 63;
    const int w    = threadIdx.x >> 6;
    if (lane == 0) sred[w] = make_float4(cnt, nll, reg, corr);
    __syncthreads();
    if (threadIdx.x == 0) {
        float4 t = make_float4(0.f, 0.f, 0.f, 0.f);
        #pragma unroll
        for (int i = 0; i < 4; ++i) {
            t.x += sred[i].x; t.y += sred[i].y; t.z += sred[i].z; t.w += sred[i].w;
        }
        part[blockIdx.x] = t;
    }
}

// Single-block tree reduce of the 4096 float4 partials + finalize.
__global__ __launch_bounds__(1024) void frcnn_reduce(
    const float4* __restrict__ part, float* __restrict__ out)
{
    __shared__ float4 sw[16];
    float4 s = make_float4(0.f, 0.f, 0.f, 0.f);
    for (int i = threadIdx.x; i < GRID_MAIN; i += 1024) {
        const float4 p = part[i];
        s.x += p.x; s.y += p.y; s.z += p.z; s.w += p.w;
    }
    #pragma unroll
    for (int off = 32; off > 0; off >>= 1) {
        s.x += __shfl_down(s.x, off);
        s.y += __shfl_down(s.y, off);
        s.z += __shfl_down(s.z, off);
        s.w += __shfl_down(s.w, off);
    }
    const int lane = threadIdx.x & 63;
    const int w    = threadIdx.x >> 6;
    if (lane == 0) sw[w] = s;
    __syncthreads();
    if (threadIdx.x == 0) {
        float4 t = make_float4(0.f, 0.f, 0.f, 0.f);
        #pragma unroll
        for (int i = 0; i < 16; ++i) {
            t.x += sw[i].x; t.y += sw[i].y; t.z += sw[i].z; t.w += sw[i].w;
        }
        const float pos   = (t.x > 0.f) ? 1.f : 0.f;
        const float denom = fmaxf(t.x, 1.f);
        out[0] = t.y / denom * pos;   // cls_loss
        out[1] = t.z / denom * pos;   // reg_loss
        out[2] = t.w / denom * pos;   // accuracy
    }
}

extern "C" void kernel_launch(void* const* d_in, const int* in_sizes, int n_in,
                              void* d_out, int out_size, void* d_ws, size_t ws_size,
                              hipStream_t stream) {
    // setup_inputs order: nms_reg, nms_cls(unused), rcnn_reg, rcnn_cls, bboxes, classes, reduction
    const float* nms_reg  = (const float*)d_in[0];
    const float* rcnn_reg = (const float*)d_in[2];
    const float* rcnn_cls = (const float*)d_in[3];
    const float* bboxes   = (const float*)d_in[4];
    const int*   classes  = (const int*)d_in[5];
    const int*   red      = (const int*)d_in[6];

    float4* part = (float4*)d_ws;   // 4096 * 16 B = 64 KiB, fully rewritten each launch

    frcnn_main<<<GRID_MAIN, 256, 0, stream>>>(nms_reg, rcnn_reg, rcnn_cls, bboxes,
                                              classes, red, part);
    frcnn_reduce<<<1, 1024, 0, stream>>>(part, (float*)d_out);
}